// Round 8
// baseline (9514.008 us; speedup 1.0000x reference)
//
#include <hip/hip_runtime.h>

typedef __attribute__((ext_vector_type(8))) short short8;
typedef __attribute__((ext_vector_type(4))) float f32x4;
typedef __attribute__((ext_vector_type(4))) int   i32x4;
typedef __attribute__((ext_vector_type(4))) float fvec4;
typedef __attribute__((ext_vector_type(4))) unsigned short u16x4;

#define B_ 64
#define T_ 256
#define H_ 512
#define NG 2048   // 4*H
#define BTH (64*256*512)
#define BH (64*512)
#define FPAD 64   // 256B per flag slot
#define RING 32   // h ring depth (tag disambiguates generations)

__device__ __forceinline__ float bf2f(unsigned short u) {
    return __builtin_bit_cast(float, ((unsigned)u) << 16);
}
__device__ __forceinline__ unsigned short f2bf(float f) {
    unsigned u = __builtin_bit_cast(unsigned, f);
    u += 0x7fffu + ((u >> 16) & 1u);   // RNE
    return (unsigned short)(u >> 16);
}
__device__ __forceinline__ float sigm(float x) { return 1.f / (1.f + __expf(-x)); }
__device__ __forceinline__ float tanh_f(float x) {
    x = fminf(15.f, fmaxf(-15.f, x));
    float e = __expf(-2.f * x);
    return (1.f - e) / (1.f + e);
}

__device__ __forceinline__ void store_coh(unsigned* p, unsigned v) {
    __hip_atomic_store(p, v, __ATOMIC_RELAXED, __HIP_MEMORY_SCOPE_AGENT);
}
__device__ __forceinline__ unsigned load_coh(const unsigned* p) {
    return __hip_atomic_load(p, __ATOMIC_RELAXED, __HIP_MEMORY_SCOPE_AGENT);
}

// ---------------- tagged cohort read (sentinel-in-data) ----------------
// ring layout: [idx RING][slot 32][col 16][b 64] u32 ; u = (tag<<16) | bf16
// Reader lane (quad,l15) builds A-frags: row = m0+l15 (batch), k-col = kb*32+quad*8+j.
// Per-load-instruction: 4 cache lines (fully coalesced). Retry until every u32's
// tag matches (per-u32 validation is immune to partial/out-of-order arrival).
__device__ __forceinline__ void tag_read(const unsigned* ring, int idx, unsigned tag,
                                         int row, int quad, short8* ha) {
    const unsigned* lanep = ring + ((size_t)idx << 15) +
                            ((quad >> 1) << 10) + ((quad & 1) << 9) + row;
    const unsigned utag = tag << 16;
    int spins = 0;
    for (;;) {
        unsigned bad = 0;
#pragma unroll
        for (int kb = 0; kb < 16; ++kb) {
            unsigned u[8];
#pragma unroll
            for (int j = 0; j < 8; ++j) {
                u[j] = load_coh(lanep + (kb << 11) + (j << 6));
                bad |= u[j] ^ utag;
            }
            i32x4 w;
            w[0] = (int)((u[0] & 0xffffu) | (u[1] << 16));
            w[1] = (int)((u[2] & 0xffffu) | (u[3] << 16));
            w[2] = (int)((u[4] & 0xffffu) | (u[5] << 16));
            w[3] = (int)((u[6] & 0xffffu) | (u[7] << 16));
            ha[kb] = __builtin_bit_cast(short8, w);
        }
        if (!__any((int)(bad & 0xffff0000u))) break;   // only tag (high16) mismatches count
        __builtin_amdgcn_s_sleep(1);
        if (++spins > 50000) break;    // failsafe: wrong answer, not hang
    }
}

// advisory back-pressure: all 32 slots' wave-w progress >= thr
__device__ __forceinline__ void bp_wait(const unsigned* prog, int w, int thr) {
    const unsigned* p = prog + (size_t)(((threadIdx.x & 31) << 2) + w) * FPAD;
    int spins = 0;
    for (;;) {
        int v = (int)load_coh(p);
        if (__all((int)(v >= thr))) break;
        __builtin_amdgcn_s_sleep(1);
        if (++spins > 400000) break;
    }
    asm volatile("" ::: "memory");
}

// ---------------- prep: weight transpose f32[K,N] -> bf16[N,K] ----------------
__global__ void transpose_cvt(const float* __restrict__ Wi, const float* __restrict__ Wh,
                              unsigned short* __restrict__ Wt) {
    __shared__ float tile[64][65];
    int z = blockIdx.z;
    const float* src = (z < 2 ? Wi : Wh) + (size_t)(z & 1) * H_ * NG;
    unsigned short* dst = Wt + (size_t)z * NG * H_;
    int k0 = blockIdx.x * 64, n0 = blockIdx.y * 64;
    int tx = threadIdx.x & 63, ty = threadIdx.x >> 6;
#pragma unroll
    for (int p = 0; p < 16; ++p) {
        int r = (p << 2) + ty;
        tile[r][tx] = src[(size_t)(k0 + r) * NG + n0 + tx];
    }
    __syncthreads();
#pragma unroll
    for (int p = 0; p < 16; ++p) {
        int r = (p << 2) + ty;
        dst[(size_t)(n0 + r) * H_ + k0 + tx] = f2bf(tile[tx][r]);
    }
}

__global__ void cvt_bf16(const float* __restrict__ x, unsigned short* __restrict__ xb) {
    size_t i = ((size_t)blockIdx.x * 256 + threadIdx.x) * 4;
    fvec4 v = *(const fvec4*)&x[i];
    u16x4 o;
    o[0] = f2bf(v[0]); o[1] = f2bf(v[1]); o[2] = f2bf(v[2]); o[3] = f2bf(v[3]);
    *(u16x4*)&xb[i] = o;
}

// ---------------- big GEMM (layer-0 input gates), blocked Gi output ------------
__global__ __launch_bounds__(256) void gemm_bt(
    const unsigned short* __restrict__ A, const unsigned short* __restrict__ Bt,
    const float* __restrict__ bias1, const float* __restrict__ bias2,
    unsigned short* __restrict__ C) {
    const int tid = threadIdx.x;
    const int wave = tid >> 6, lane = tid & 63;
    const int quad = lane >> 4, l15 = lane & 15;
    const int row0 = blockIdx.x * 64 + wave * 16;
    const int col0 = blockIdx.y * 64;
    f32x4 acc[4] = {};
    const unsigned short* ap = A + (size_t)(row0 + l15) * H_ + (quad << 3);
    const unsigned short* bp = Bt + (size_t)(col0 + l15) * H_ + (quad << 3);
#pragma unroll
    for (int kk = 0; kk < H_; kk += 32) {
        short8 a = *(const short8*)(ap + kk);
#pragma unroll
        for (int c4 = 0; c4 < 4; ++c4) {
            short8 b = *(const short8*)(bp + (size_t)(c4 << 4) * H_ + kk);
            acc[c4] = __builtin_amdgcn_mfma_f32_16x16x32_bf16(a, b, acc[c4], 0, 0, 0);
        }
    }
#pragma unroll
    for (int c4 = 0; c4 < 4; ++c4) {
        int col = col0 + (c4 << 4) + l15;
        float bs = bias1[col] + bias2[col];
        int g = col >> 9;
        int blk = (col & 511) >> 4;
#pragma unroll
        for (int r = 0; r < 4; ++r) {
            int row = row0 + (quad << 2) + r;
            int t = row & 255, b = row >> 8;
            C[((size_t)blk << 20) + ((size_t)t << 12) + (g << 10) + (b << 4) + l15] =
                f2bf(acc[c4][r] + bs);
        }
    }
}

// ---------------- fused persistent 2-layer recurrent kernel ----------------
// 64 WGs x 256 thr. WGs 0..31: layer 0; WGs 32..63: layer 1.
// h exchange: tagged u32 rings (sentinel-in-data). Producer stores are the
// publication (no drain, no flags, no barriers in the steady loop). Ring depth
// 32; zeroed ring = valid h(-1)=0 (tag 0). L0->L1 overwrite bounded by an
// advisory progress flag checked every 8 steps with 23-step margin.
__global__ __launch_bounds__(256, 1) void lstm_fused(
    const unsigned short* __restrict__ Gi,   // blocked layer-0 gates (incl. biases)
    const unsigned short* __restrict__ Wt,   // 4 slabs: Wi0^T, Wi1^T, Wh0^T, Wh1^T
    unsigned* __restrict__ h0r,              // tagged ring [32][32][16][64] u32
    unsigned* __restrict__ h1r,              // tagged ring
    const float* __restrict__ bi, const float* __restrict__ bh,
    float* __restrict__ out,                 // [B][T][512] f32 (layer-1 output)
    float* __restrict__ hT, float* __restrict__ cT,   // [L][B][512]
    unsigned* __restrict__ prog) {           // L1 progress flags [slot*4+wave]*FPAD
    __shared__ unsigned short wi_lds[64 * 512];   // 64KB, fragment-linear layout
    const size_t NK = (size_t)NG * H_;
    const int tid = threadIdx.x;
    const int wave = tid >> 6, lane = tid & 63;
    const int quad = lane >> 4, l15 = lane & 15;
    const int m0 = wave << 4;
    const int arow = m0 + l15;   // A-frag row (batch index)

    if (blockIdx.x < 32) {
        // ================= layer 0 =================
        const int slot = (int)blockIdx.x;
        const int j0 = slot << 4;
        const unsigned short* Wht = Wt + 2 * NK;
        short8 bw[64];
#pragma unroll
        for (int kb = 0; kb < 16; ++kb)
#pragma unroll
            for (int g = 0; g < 4; ++g)
                bw[kb * 4 + g] =
                    *(const short8*)&Wht[(size_t)((g << 9) + j0 + l15) * H_ + (kb << 5) + (quad << 3)];
#pragma unroll
        for (int i = 0; i < 64; ++i) asm volatile("" : "+v"(bw[i]));

        float cc[4] = {0.f, 0.f, 0.f, 0.f};

        for (int t = 0; t < T_; ++t) {
            // Gi[t] plain loads (in flight during tagged polls)
            float gv[4][4];
#pragma unroll
            for (int r = 0; r < 4; ++r) {
                int b = m0 + (quad << 2) + r;
#pragma unroll
                for (int g = 0; g < 4; ++g)
                    gv[g][r] = bf2f(Gi[((size_t)slot << 20) + ((size_t)t << 12) +
                                       (g << 10) + (b << 4) + l15]);
            }

            // h0(t-1): tagged cohort read (self-validating)
            short8 ha[16];
            tag_read(h0r, t & (RING - 1), (unsigned)t, arow, quad, ha);

            f32x4 acc0 = {}, acc1 = {}, acc2 = {}, acc3 = {};
#pragma unroll
            for (int kb = 0; kb < 16; ++kb) {
                acc0 = __builtin_amdgcn_mfma_f32_16x16x32_bf16(ha[kb], bw[kb * 4 + 0], acc0, 0, 0, 0);
                acc1 = __builtin_amdgcn_mfma_f32_16x16x32_bf16(ha[kb], bw[kb * 4 + 1], acc1, 0, 0, 0);
                acc2 = __builtin_amdgcn_mfma_f32_16x16x32_bf16(ha[kb], bw[kb * 4 + 2], acc2, 0, 0, 0);
                acc3 = __builtin_amdgcn_mfma_f32_16x16x32_bf16(ha[kb], bw[kb * 4 + 3], acc3, 0, 0, 0);
            }

            // back-pressure vs layer 1 (amortized 1/8 steps; margin covers t..t+7)
            if ((t & 7) == 0 && t >= 24) bp_wait(prog, wave, t - 23);

            // elementwise + tagged store of h0(t): the store IS the publication
            unsigned* hw = h0r + ((size_t)((t + 1) & (RING - 1)) << 15) +
                           ((size_t)slot << 10) + ((size_t)l15 << 6) + m0;
            const unsigned utagw = (unsigned)(t + 1) << 16;
            float hvv[4];
#pragma unroll
            for (int r = 0; r < 4; ++r) {
                float iv = sigm(acc0[r] + gv[0][r]);
                float fv = sigm(acc1[r] + gv[1][r]);
                float gg = tanh_f(acc2[r] + gv[2][r]);
                float ov = sigm(acc3[r] + gv[3][r]);
                float cn = fv * cc[r] + iv * gg;
                cc[r] = cn;
                float hv = ov * tanh_f(cn);
                hvv[r] = hv;
                store_coh(&hw[(quad << 2) + r], utagw | (unsigned)f2bf(hv));
            }
            if (t == T_ - 1) {
#pragma unroll
                for (int r = 0; r < 4; ++r) {
                    int b = m0 + (quad << 2) + r;
                    int jj = j0 + l15;
                    hT[((size_t)b << 9) + jj] = hvv[r];
                    cT[((size_t)b << 9) + jj] = cc[r];
                }
            }
        }
    } else {
        // ================= layer 1 =================
        const int slot = (int)blockIdx.x - 32;
        const int j0 = slot << 4;
        const unsigned short* Wht = Wt + 3 * NK;
        short8 bw[64];
#pragma unroll
        for (int kb = 0; kb < 16; ++kb)
#pragma unroll
            for (int g = 0; g < 4; ++g)
                bw[kb * 4 + g] =
                    *(const short8*)&Wht[(size_t)((g << 9) + j0 + l15) * H_ + (kb << 5) + (quad << 3)];
#pragma unroll
        for (int i = 0; i < 64; ++i) asm volatile("" : "+v"(bw[i]));

        // stage Wi1 slab into LDS (byte = kb*4096 + g*1024 + quad*256 + l15*16)
        const unsigned short* Wit = Wt + 1 * NK;
#pragma unroll
        for (int i2 = 0; i2 < 16; ++i2) {
            int c = i2 * 256 + tid;            // 4096 x 16B chunks
            int l = c & 15, q = (c >> 4) & 3, g = (c >> 6) & 3, kb = c >> 8;
            short8 v = *(const short8*)&Wit[(size_t)((g << 9) + j0 + l) * H_ + (kb << 5) + (q << 3)];
            *(short8*)((char*)wi_lds + ((size_t)c << 4)) = v;
        }
        __syncthreads();   // one-time: LDS staging visible to all waves
        const int wbase = (quad << 8) + (l15 << 4);

        float gb0 = bi[NG + j0 + l15]        + bh[NG + j0 + l15];
        float gb1 = bi[NG + 512 + j0 + l15]  + bh[NG + 512 + j0 + l15];
        float gb2 = bi[NG + 1024 + j0 + l15] + bh[NG + 1024 + j0 + l15];
        float gb3 = bi[NG + 1536 + j0 + l15] + bh[NG + 1536 + j0 + l15];

        float cc[4] = {0.f, 0.f, 0.f, 0.f};

        for (int t = 0; t < T_; ++t) {
            // h0(t): L0 runs ahead -> usually first-try; read first, then publish progress
            short8 ha0[16], ha1[16];
            tag_read(h0r, (t + 1) & (RING - 1), (unsigned)(t + 1), arow, quad, ha0);
            if (lane == 0)
                store_coh(&prog[(size_t)((slot << 2) + wave) * FPAD], (unsigned)(t + 1));
            // h1(t-1): own cohort (the gating read)
            tag_read(h1r, t & (RING - 1), (unsigned)t, arow, quad, ha1);

            f32x4 acc0 = {}, acc1 = {}, acc2 = {}, acc3 = {};
#pragma unroll
            for (int kb = 0; kb < 16; ++kb) {
                acc0 = __builtin_amdgcn_mfma_f32_16x16x32_bf16(ha1[kb], bw[kb * 4 + 0], acc0, 0, 0, 0);
                acc1 = __builtin_amdgcn_mfma_f32_16x16x32_bf16(ha1[kb], bw[kb * 4 + 1], acc1, 0, 0, 0);
                acc2 = __builtin_amdgcn_mfma_f32_16x16x32_bf16(ha1[kb], bw[kb * 4 + 2], acc2, 0, 0, 0);
                acc3 = __builtin_amdgcn_mfma_f32_16x16x32_bf16(ha1[kb], bw[kb * 4 + 3], acc3, 0, 0, 0);
            }
#pragma unroll
            for (int kb = 0; kb < 16; ++kb) {
                const char* base = (const char*)wi_lds + (kb << 12) + wbase;
                short8 w0 = *(const short8*)(base);
                short8 w1 = *(const short8*)(base + (1 << 10));
                short8 w2 = *(const short8*)(base + (2 << 10));
                short8 w3 = *(const short8*)(base + (3 << 10));
                acc0 = __builtin_amdgcn_mfma_f32_16x16x32_bf16(ha0[kb], w0, acc0, 0, 0, 0);
                acc1 = __builtin_amdgcn_mfma_f32_16x16x32_bf16(ha0[kb], w1, acc1, 0, 0, 0);
                acc2 = __builtin_amdgcn_mfma_f32_16x16x32_bf16(ha0[kb], w2, acc2, 0, 0, 0);
                acc3 = __builtin_amdgcn_mfma_f32_16x16x32_bf16(ha0[kb], w3, acc3, 0, 0, 0);
            }

            unsigned* hw = h1r + ((size_t)((t + 1) & (RING - 1)) << 15) +
                           ((size_t)slot << 10) + ((size_t)l15 << 6) + m0;
            const unsigned utagw = (unsigned)(t + 1) << 16;
            float hvv[4];
#pragma unroll
            for (int r = 0; r < 4; ++r) {
                float iv = sigm(acc0[r] + gb0);
                float fv = sigm(acc1[r] + gb1);
                float gg = tanh_f(acc2[r] + gb2);
                float ov = sigm(acc3[r] + gb3);
                float cn = fv * cc[r] + iv * gg;
                cc[r] = cn;
                float hv = ov * tanh_f(cn);
                hvv[r] = hv;
                store_coh(&hw[(quad << 2) + r], utagw | (unsigned)f2bf(hv));
            }
#pragma unroll
            for (int r = 0; r < 4; ++r) {
                int b = m0 + (quad << 2) + r;
                int jj = j0 + l15;
                out[((size_t)((b << 8) + t)) * H_ + jj] = hvv[r];
            }
            if (t == T_ - 1) {
#pragma unroll
                for (int r = 0; r < 4; ++r) {
                    int b = m0 + (quad << 2) + r;
                    int jj = j0 + l15;
                    hT[BH + ((size_t)b << 9) + jj] = hvv[r];
                    cT[BH + ((size_t)b << 9) + jj] = cc[r];
                }
            }
        }
    }
}

extern "C" void kernel_launch(void* const* d_in, const int* in_sizes, int n_in,
                              void* d_out, int out_size, void* d_ws, size_t ws_size,
                              hipStream_t stream) {
    const float* x  = (const float*)d_in[0];
    const float* Wi = (const float*)d_in[1];
    const float* Wh = (const float*)d_in[2];
    const float* bi = (const float*)d_in[3];
    const float* bh = (const float*)d_in[4];
    float* out = (float*)d_out;

    char* w = (char*)d_ws;
    const size_t NK = (size_t)NG * H_;
    unsigned short* Wt  = (unsigned short*)w;                  // 8 MB (4 slabs)
    unsigned short* xb  = Wt + 4 * NK;                         // 16 MB
    unsigned short* Gi  = xb + (size_t)16384 * H_;             // 64 MB (blocked layout)
    unsigned* h0rg      = (unsigned*)(Gi + (size_t)16384 * NG);// 4 MB tagged ring
    unsigned* h1rg      = h0rg + ((size_t)RING << 15);         // 4 MB tagged ring
    unsigned* prog      = h1rg + ((size_t)RING << 15);         // 32 KB progress flags

    // zeroed ring == valid h(-1)=0 with tag 0; must reset every launch (tag reuse)
    hipMemsetAsync(h0rg, 0, (size_t)RING << 17, stream);
    hipMemsetAsync(h1rg, 0, (size_t)RING << 17, stream);
    hipMemsetAsync(prog, 0, 128 * FPAD * sizeof(unsigned), stream);

    transpose_cvt<<<dim3(8, 32, 4), 256, 0, stream>>>(Wi, Wh, Wt);
    cvt_bf16<<<8192, 256, 0, stream>>>(x, xb);

    // layer-0 input gates (bulk GEMM, biases baked in, blocked output)
    gemm_bt<<<dim3(256, 32), 256, 0, stream>>>(xb, Wt + 0 * NK, bi, bh, Gi);

    // fused pipelined 2-layer recurrence (sentinel-in-data exchange)
    lstm_fused<<<64, 256, 0, stream>>>(Gi, Wt, h0rg, h1rg, bi, bh,
                                       out, out + BTH, out + BTH + 2 * (size_t)BH, prog);
}

// Round 9
// 2965.760 us; speedup vs baseline: 3.2079x; 3.2079x over previous
//
#include <hip/hip_runtime.h>

typedef __attribute__((ext_vector_type(8))) short short8;
typedef __attribute__((ext_vector_type(4))) float f32x4;
typedef __attribute__((ext_vector_type(4))) float fvec4;
typedef __attribute__((ext_vector_type(4))) unsigned short u16x4;

#define B_ 64
#define T_ 256
#define H_ 512
#define NG 2048   // 4*H
#define BTH (64*256*512)
#define BH (64*512)
#define FPAD 64   // 256B per flag slot -> distinct L3 lines

__device__ __forceinline__ float bf2f(unsigned short u) {
    return __builtin_bit_cast(float, ((unsigned)u) << 16);
}
__device__ __forceinline__ unsigned short f2bf(float f) {
    unsigned u = __builtin_bit_cast(unsigned, f);
    u += 0x7fffu + ((u >> 16) & 1u);   // RNE
    return (unsigned short)(u >> 16);
}
__device__ __forceinline__ float sigm(float x) { return 1.f / (1.f + __expf(-x)); }
__device__ __forceinline__ float tanh_f(float x) {
    x = fminf(15.f, fmaxf(-15.f, x));
    float e = __expf(-2.f * x);
    return (1.f - e) / (1.f + e);
}

__device__ __forceinline__ void store_coh(unsigned* p, unsigned v) {
    __hip_atomic_store(p, v, __ATOMIC_RELAXED, __HIP_MEMORY_SCOPE_AGENT);
}
// drain this wave's outstanding vmem ops (stores acked at coherence point)
__device__ __forceinline__ void drain_vm() {
    asm volatile("s_waitcnt vmcnt(0)" ::: "memory");
}
// wave-cohort wait: poll the 32 flags of wave-index w across the 32 WG slots.
__device__ __forceinline__ void wv_wait(const unsigned* fl, int w, unsigned target) {
    const unsigned* p = fl + (size_t)(((threadIdx.x & 31) << 2) + w) * FPAD;
    int spins = 0;
    for (;;) {
        unsigned v = __hip_atomic_load(p, __ATOMIC_RELAXED, __HIP_MEMORY_SCOPE_AGENT);
        if (__all((int)(v >= target))) break;
        __builtin_amdgcn_s_sleep(1);
        if (++spins > 400000) break;   // failsafe: wrong answer, not hang
    }
    asm volatile("" ::: "memory");     // no hoisting of data loads above the poll
}
// dual cohort wait in ONE poll round: lanes 0..31 -> fA>=tA, lanes 32..63 -> fB>=tB
__device__ __forceinline__ void wv_wait2(const unsigned* fA, unsigned tA,
                                         const unsigned* fB, unsigned tB, int w) {
    const int l = threadIdx.x & 63;
    const unsigned* p = (l < 32) ? fA + (size_t)(((l & 31) << 2) + w) * FPAD
                                 : fB + (size_t)(((l & 31) << 2) + w) * FPAD;
    const unsigned tgt = (l < 32) ? tA : tB;
    int spins = 0;
    for (;;) {
        unsigned v = __hip_atomic_load(p, __ATOMIC_RELAXED, __HIP_MEMORY_SCOPE_AGENT);
        if (__all((int)(v >= tgt))) break;
        __builtin_amdgcn_s_sleep(1);
        if (++spins > 400000) break;
    }
    asm volatile("" ::: "memory");
}

// ---------------- prep: weight transpose f32[K,N] -> bf16[N,K] ----------------
__global__ void transpose_cvt(const float* __restrict__ Wi, const float* __restrict__ Wh,
                              unsigned short* __restrict__ Wt) {
    __shared__ float tile[64][65];
    int z = blockIdx.z;
    const float* src = (z < 2 ? Wi : Wh) + (size_t)(z & 1) * H_ * NG;
    unsigned short* dst = Wt + (size_t)z * NG * H_;
    int k0 = blockIdx.x * 64, n0 = blockIdx.y * 64;
    int tx = threadIdx.x & 63, ty = threadIdx.x >> 6;
#pragma unroll
    for (int p = 0; p < 16; ++p) {
        int r = (p << 2) + ty;
        tile[r][tx] = src[(size_t)(k0 + r) * NG + n0 + tx];
    }
    __syncthreads();
#pragma unroll
    for (int p = 0; p < 16; ++p) {
        int r = (p << 2) + ty;
        dst[(size_t)(n0 + r) * H_ + k0 + tx] = f2bf(tile[tx][r]);
    }
}

// x [B][T][H] f32 -> xb [t][b][h] bf16 (blocked for the fused L0 input GEMM)
__global__ void cvt_blk(const float* __restrict__ x, unsigned short* __restrict__ xb) {
    size_t i = ((size_t)blockIdx.x * 256 + threadIdx.x) * 4;
    int h = (int)(i & 511);
    size_t r2 = i >> 9;
    int t = (int)(r2 & 255), b = (int)(r2 >> 8);
    fvec4 v = *(const fvec4*)&x[i];
    u16x4 o;
    o[0] = f2bf(v[0]); o[1] = f2bf(v[1]); o[2] = f2bf(v[2]); o[3] = f2bf(v[3]);
    *(u16x4*)&xb[(((size_t)t << 6) + b) * H_ + h] = o;
}

// ---------------- fused persistent 2-layer recurrent kernel ----------------
// 64 WGs x 256 thr. WGs 0..31: layer 0; WGs 32..63: layer 1 (lags >=1 step).
// BOTH layers: Wh slab in VGPRs (64 frags), Wi slab in LDS (fragment-linear),
// A-operands = {streamed input (xb for L0, h0 history for L1)} + {own-layer
// h(t-1) cohort read}. Input GEMM fully fused: no bulk GEMM, no Gi buffer.
// h exchange: write-once histories h[t][slot][b][8u32]; per-wave flags;
// producer: sc1 stores -> vmcnt(0) -> own-flag store; consumer: flag poll ->
// plain vectorized loads. No __syncthreads in the steady loop.
__global__ __launch_bounds__(256, 1) void lstm_fused(
    const unsigned short* __restrict__ xb,   // [t][b][512] bf16
    const unsigned short* __restrict__ Wt,   // 4 slabs: Wi0^T, Wi1^T, Wh0^T, Wh1^T
    unsigned* __restrict__ h0h,              // [T+1][32][64][8] u32 h0 history
    unsigned* __restrict__ h1h,              // [T+1][32][64][8] u32 h1 history
    const float* __restrict__ bi, const float* __restrict__ bh,
    float* __restrict__ out,                 // [B][T][512] f32 (layer-1 output)
    float* __restrict__ hT, float* __restrict__ cT,   // [L][B][512]
    unsigned* __restrict__ flags) {          // [layer][slot*4+wave]*FPAD
    __shared__ unsigned short wi_lds[64 * 512];   // 64KB, fragment-linear
    const size_t NK = (size_t)NG * H_;
    const int tid = threadIdx.x;
    const int wave = tid >> 6, lane = tid & 63;
    const int quad = lane >> 4, l15 = lane & 15;
    const int m0 = wave << 4;
    unsigned* flag0 = flags;
    unsigned* flag1 = flags + 128 * FPAD;
    // per-lane offset into a t-slab of the h history (reader side)
    const size_t hoff = ((size_t)(quad >> 1) << 9) + ((size_t)(m0 + l15) << 3) + ((quad & 1) << 2);
    const int wbase = (quad << 8) + (l15 << 4);
    const int is_l1 = (blockIdx.x >= 32);
    const int slot = (int)blockIdx.x & 31;
    const int j0 = slot << 4;

    // ---- Wh slab -> VGPRs ----
    const unsigned short* Wht = Wt + (is_l1 ? 3 : 2) * NK;
    short8 bw[64];
#pragma unroll
    for (int kb = 0; kb < 16; ++kb)
#pragma unroll
        for (int g = 0; g < 4; ++g)
            bw[kb * 4 + g] =
                *(const short8*)&Wht[(size_t)((g << 9) + j0 + l15) * H_ + (kb << 5) + (quad << 3)];
#pragma unroll
    for (int i = 0; i < 64; ++i) asm volatile("" : "+v"(bw[i]));

    // ---- Wi slab -> LDS (byte = kb*4096 + g*1024 + quad*256 + l15*16) ----
    const unsigned short* Wit = Wt + (is_l1 ? 1 : 0) * NK;
#pragma unroll
    for (int i2 = 0; i2 < 16; ++i2) {
        int c = i2 * 256 + tid;            // 4096 x 16B chunks
        int l = c & 15, q = (c >> 4) & 3, g = (c >> 6) & 3, kb = c >> 8;
        short8 v = *(const short8*)&Wit[(size_t)((g << 9) + j0 + l) * H_ + (kb << 5) + (q << 3)];
        *(short8*)((char*)wi_lds + ((size_t)c << 4)) = v;
    }
    __syncthreads();   // one-time: LDS staging visible to all waves

    // ---- biases ----
    const int boff = is_l1 ? NG : 0;
    float gb0 = bi[boff + j0 + l15]        + bh[boff + j0 + l15];
    float gb1 = bi[boff + 512 + j0 + l15]  + bh[boff + 512 + j0 + l15];
    float gb2 = bi[boff + 1024 + j0 + l15] + bh[boff + 1024 + j0 + l15];
    float gb3 = bi[boff + 1536 + j0 + l15] + bh[boff + 1536 + j0 + l15];

    float cc[4] = {0.f, 0.f, 0.f, 0.f};

    if (!is_l1) {
        // ================= layer 0 =================
        // zero own rows of h0 slot 0 (slot-major layout)
        if (!(l15 & 1)) {
            unsigned* hz = h0h + ((size_t)(slot * 64) << 3) + (l15 >> 1);
#pragma unroll
            for (int r = 0; r < 4; ++r)
                store_coh(&hz[(size_t)(m0 + (quad << 2) + r) << 3], 0u);
        }
        drain_vm();
        store_coh(&flag0[(size_t)((slot << 2) + wave) * FPAD], 1u);

        // preload x A-frags for t=0
        short8 xa[16];
        {
            const unsigned short* xp = xb + (size_t)(m0 + l15) * H_ + (quad << 3);
#pragma unroll
            for (int kb = 0; kb < 16; ++kb) xa[kb] = *(const short8*)(xp + (kb << 5));
        }

        for (int t = 0; t < T_; ++t) {
            wv_wait(flag0, wave, (unsigned)(t + 1));
            const unsigned* ap = h0h + ((size_t)t << 14) + hoff;
            short8 ha[16];
#pragma unroll
            for (int kb = 0; kb < 16; ++kb) ha[kb] = *(const short8*)(ap + (kb << 10));

            f32x4 acc0 = {}, acc1 = {}, acc2 = {}, acc3 = {};
            // Wh0 x h0(t-1)
#pragma unroll
            for (int kb = 0; kb < 16; ++kb) {
                acc0 = __builtin_amdgcn_mfma_f32_16x16x32_bf16(ha[kb], bw[kb * 4 + 0], acc0, 0, 0, 0);
                acc1 = __builtin_amdgcn_mfma_f32_16x16x32_bf16(ha[kb], bw[kb * 4 + 1], acc1, 0, 0, 0);
                acc2 = __builtin_amdgcn_mfma_f32_16x16x32_bf16(ha[kb], bw[kb * 4 + 2], acc2, 0, 0, 0);
                acc3 = __builtin_amdgcn_mfma_f32_16x16x32_bf16(ha[kb], bw[kb * 4 + 3], acc3, 0, 0, 0);
            }
            // Wi0 x x(t) (B-frags from LDS)
#pragma unroll
            for (int kb = 0; kb < 16; ++kb) {
                const char* base = (const char*)wi_lds + (kb << 12) + wbase;
                short8 w0 = *(const short8*)(base);
                short8 w1 = *(const short8*)(base + (1 << 10));
                short8 w2 = *(const short8*)(base + (2 << 10));
                short8 w3 = *(const short8*)(base + (3 << 10));
                acc0 = __builtin_amdgcn_mfma_f32_16x16x32_bf16(xa[kb], w0, acc0, 0, 0, 0);
                acc1 = __builtin_amdgcn_mfma_f32_16x16x32_bf16(xa[kb], w1, acc1, 0, 0, 0);
                acc2 = __builtin_amdgcn_mfma_f32_16x16x32_bf16(xa[kb], w2, acc2, 0, 0, 0);
                acc3 = __builtin_amdgcn_mfma_f32_16x16x32_bf16(xa[kb], w3, acc3, 0, 0, 0);
            }

            unsigned* hw = h0h + ((size_t)(t + 1) << 14) + ((size_t)(slot * 64) << 3) + (l15 >> 1);
            float hvv[4];
#pragma unroll
            for (int r = 0; r < 4; ++r) {
                float iv = sigm(acc0[r] + gb0);
                float fv = sigm(acc1[r] + gb1);
                float gg = tanh_f(acc2[r] + gb2);
                float ov = sigm(acc3[r] + gb3);
                float cn = fv * cc[r] + iv * gg;
                cc[r] = cn;
                float hv = ov * tanh_f(cn);
                hvv[r] = hv;
                unsigned short hb16 = f2bf(hv);
                unsigned packed = (unsigned)hb16 |
                                  (((unsigned)(unsigned short)__shfl_xor((int)hb16, 1)) << 16);
                if (!(l15 & 1))
                    store_coh(&hw[(size_t)(m0 + (quad << 2) + r) << 3], packed);
            }
            drain_vm();   // only the 4 h stores outstanding here
            store_coh(&flag0[(size_t)((slot << 2) + wave) * FPAD], (unsigned)(t + 2));

            if (t < T_ - 1) {
                // prefetch x A-frags for t+1 (in flight during next wait)
                const unsigned short* xp =
                    xb + (((size_t)(t + 1) << 6) + (m0 + l15)) * H_ + (quad << 3);
#pragma unroll
                for (int kb = 0; kb < 16; ++kb) xa[kb] = *(const short8*)(xp + (kb << 5));
            } else {
#pragma unroll
                for (int r = 0; r < 4; ++r) {
                    int b = m0 + (quad << 2) + r;
                    int jj = j0 + l15;
                    hT[((size_t)b << 9) + jj] = hvv[r];
                    cT[((size_t)b << 9) + jj] = cc[r];
                }
            }
        }
    } else {
        // ================= layer 1 =================
        // zero own rows of h1 slot 0
        if (!(l15 & 1)) {
            unsigned* hz = h1h + ((size_t)(slot * 64) << 3) + (l15 >> 1);
#pragma unroll
            for (int r = 0; r < 4; ++r)
                store_coh(&hz[(size_t)(m0 + (quad << 2) + r) << 3], 0u);
        }
        drain_vm();
        store_coh(&flag1[(size_t)((slot << 2) + wave) * FPAD], 1u);

        for (int t = 0; t < T_; ++t) {
            // one dual poll: own cohort h1(t-1) AND layer-0 h0(t)
            wv_wait2(flag1, (unsigned)(t + 1), flag0, (unsigned)(t + 2), wave);
            const unsigned* ap1 = h1h + ((size_t)t << 14) + hoff;
            const unsigned* ap0 = h0h + ((size_t)(t + 1) << 14) + hoff;
            short8 ha1[16], ha0[16];
#pragma unroll
            for (int kb = 0; kb < 16; ++kb) ha1[kb] = *(const short8*)(ap1 + (kb << 10));
#pragma unroll
            for (int kb = 0; kb < 16; ++kb) ha0[kb] = *(const short8*)(ap0 + (kb << 10));

            f32x4 acc0 = {}, acc1 = {}, acc2 = {}, acc3 = {};
            // Wh1 x h1(t-1)
#pragma unroll
            for (int kb = 0; kb < 16; ++kb) {
                acc0 = __builtin_amdgcn_mfma_f32_16x16x32_bf16(ha1[kb], bw[kb * 4 + 0], acc0, 0, 0, 0);
                acc1 = __builtin_amdgcn_mfma_f32_16x16x32_bf16(ha1[kb], bw[kb * 4 + 1], acc1, 0, 0, 0);
                acc2 = __builtin_amdgcn_mfma_f32_16x16x32_bf16(ha1[kb], bw[kb * 4 + 2], acc2, 0, 0, 0);
                acc3 = __builtin_amdgcn_mfma_f32_16x16x32_bf16(ha1[kb], bw[kb * 4 + 3], acc3, 0, 0, 0);
            }
            // Wi1 x h0(t) (B-frags from LDS)
#pragma unroll
            for (int kb = 0; kb < 16; ++kb) {
                const char* base = (const char*)wi_lds + (kb << 12) + wbase;
                short8 w0 = *(const short8*)(base);
                short8 w1 = *(const short8*)(base + (1 << 10));
                short8 w2 = *(const short8*)(base + (2 << 10));
                short8 w3 = *(const short8*)(base + (3 << 10));
                acc0 = __builtin_amdgcn_mfma_f32_16x16x32_bf16(ha0[kb], w0, acc0, 0, 0, 0);
                acc1 = __builtin_amdgcn_mfma_f32_16x16x32_bf16(ha0[kb], w1, acc1, 0, 0, 0);
                acc2 = __builtin_amdgcn_mfma_f32_16x16x32_bf16(ha0[kb], w2, acc2, 0, 0, 0);
                acc3 = __builtin_amdgcn_mfma_f32_16x16x32_bf16(ha0[kb], w3, acc3, 0, 0, 0);
            }

            unsigned* hw = h1h + ((size_t)(t + 1) << 14) + ((size_t)(slot * 64) << 3) + (l15 >> 1);
            float hvv[4];
#pragma unroll
            for (int r = 0; r < 4; ++r) {
                float iv = sigm(acc0[r] + gb0);
                float fv = sigm(acc1[r] + gb1);
                float gg = tanh_f(acc2[r] + gb2);
                float ov = sigm(acc3[r] + gb3);
                float cn = fv * cc[r] + iv * gg;
                cc[r] = cn;
                float hv = ov * tanh_f(cn);
                hvv[r] = hv;
                unsigned short hb16 = f2bf(hv);
                unsigned packed = (unsigned)hb16 |
                                  (((unsigned)(unsigned short)__shfl_xor((int)hb16, 1)) << 16);
                if (!(l15 & 1))
                    store_coh(&hw[(size_t)(m0 + (quad << 2) + r) << 3], packed);
            }
            drain_vm();   // only the 4 h stores outstanding
            store_coh(&flag1[(size_t)((slot << 2) + wave) * FPAD], (unsigned)(t + 2));

            // out stores AFTER publish (latency off the cohort-visible path)
#pragma unroll
            for (int r = 0; r < 4; ++r) {
                int b = m0 + (quad << 2) + r;
                int jj = j0 + l15;
                out[((size_t)((b << 8) + t)) * H_ + jj] = hvv[r];
            }
            if (t == T_ - 1) {
#pragma unroll
                for (int r = 0; r < 4; ++r) {
                    int b = m0 + (quad << 2) + r;
                    int jj = j0 + l15;
                    hT[BH + ((size_t)b << 9) + jj] = hvv[r];
                    cT[BH + ((size_t)b << 9) + jj] = cc[r];
                }
            }
        }
    }
}

extern "C" void kernel_launch(void* const* d_in, const int* in_sizes, int n_in,
                              void* d_out, int out_size, void* d_ws, size_t ws_size,
                              hipStream_t stream) {
    const float* x  = (const float*)d_in[0];
    const float* Wi = (const float*)d_in[1];
    const float* Wh = (const float*)d_in[2];
    const float* bi = (const float*)d_in[3];
    const float* bh = (const float*)d_in[4];
    float* out = (float*)d_out;

    char* w = (char*)d_ws;
    const size_t NK = (size_t)NG * H_;
    unsigned short* Wt  = (unsigned short*)w;                  // 8 MB (4 slabs)
    unsigned short* xb  = Wt + 4 * NK;                         // 16 MB (blocked [t][b][h])
    unsigned* h0h       = (unsigned*)(xb + (size_t)16384 * H_);// (T+1)*16384 u32 = 16.85 MB
    unsigned* h1h       = h0h + (size_t)(T_ + 1) * 16384;      // 16.85 MB
    unsigned* flags     = h1h + (size_t)(T_ + 1) * 16384;      // 2*128*256B = 128 KB

    hipMemsetAsync(flags, 0, 2 * 128 * FPAD * sizeof(unsigned), stream);

    transpose_cvt<<<dim3(8, 32, 4), 256, 0, stream>>>(Wi, Wh, Wt);
    cvt_blk<<<8192, 256, 0, stream>>>(x, xb);

    // fused 2-layer recurrence with fused input GEMMs (no bulk GEMM, no Gi)
    lstm_fused<<<64, 256, 0, stream>>>(xb, Wt, h0h, h1h, bi, bh,
                                       out, out + BTH, out + BTH + 2 * (size_t)BH, flags);
}

// Round 10
// 2465.723 us; speedup vs baseline: 3.8585x; 1.2028x over previous
//
#include <hip/hip_runtime.h>

typedef __attribute__((ext_vector_type(8))) short short8;
typedef __attribute__((ext_vector_type(4))) float f32x4;
typedef __attribute__((ext_vector_type(4))) float fvec4;
typedef __attribute__((ext_vector_type(4))) unsigned short u16x4;

#define B_ 64
#define T_ 256
#define H_ 512
#define NG 2048   // 4*H
#define BTH (64*256*512)
#define BH (64*512)
#define FPAD 64   // 256B per flag slot -> distinct L3 lines

__device__ __forceinline__ float bf2f(unsigned short u) {
    return __builtin_bit_cast(float, ((unsigned)u) << 16);
}
__device__ __forceinline__ unsigned short f2bf(float f) {
    unsigned u = __builtin_bit_cast(unsigned, f);
    u += 0x7fffu + ((u >> 16) & 1u);   // RNE
    return (unsigned short)(u >> 16);
}
__device__ __forceinline__ float sigm(float x) { return 1.f / (1.f + __expf(-x)); }
__device__ __forceinline__ float tanh_f(float x) {
    x = fminf(15.f, fmaxf(-15.f, x));
    float e = __expf(-2.f * x);
    return (1.f - e) / (1.f + e);
}

__device__ __forceinline__ void store_coh(unsigned* p, unsigned v) {
    __hip_atomic_store(p, v, __ATOMIC_RELAXED, __HIP_MEMORY_SCOPE_AGENT);
}
// drain this wave's outstanding vmem ops (stores acked at coherence point)
__device__ __forceinline__ void drain_vm() {
    asm volatile("s_waitcnt vmcnt(0)" ::: "memory");
}
// wave-cohort wait: poll the 32 flags of wave-index w across the 32 WG slots.
__device__ __forceinline__ void wv_wait(const unsigned* fl, int w, unsigned target) {
    const unsigned* p = fl + (size_t)(((threadIdx.x & 31) << 2) + w) * FPAD;
    int spins = 0;
    for (;;) {
        unsigned v = __hip_atomic_load(p, __ATOMIC_RELAXED, __HIP_MEMORY_SCOPE_AGENT);
        if (__all((int)(v >= target))) break;
        __builtin_amdgcn_s_sleep(1);
        if (++spins > 400000) break;   // failsafe: wrong answer, not hang
    }
    asm volatile("" ::: "memory");     // no hoisting of data loads above the poll
}

// ---------------- prep: weight transpose f32[K,N] -> bf16[N,K] ----------------
__global__ void transpose_cvt(const float* __restrict__ Wi, const float* __restrict__ Wh,
                              unsigned short* __restrict__ Wt) {
    __shared__ float tile[64][65];
    int z = blockIdx.z;
    const float* src = (z < 2 ? Wi : Wh) + (size_t)(z & 1) * H_ * NG;
    unsigned short* dst = Wt + (size_t)z * NG * H_;
    int k0 = blockIdx.x * 64, n0 = blockIdx.y * 64;
    int tx = threadIdx.x & 63, ty = threadIdx.x >> 6;
#pragma unroll
    for (int p = 0; p < 16; ++p) {
        int r = (p << 2) + ty;
        tile[r][tx] = src[(size_t)(k0 + r) * NG + n0 + tx];
    }
    __syncthreads();
#pragma unroll
    for (int p = 0; p < 16; ++p) {
        int r = (p << 2) + ty;
        dst[(size_t)(n0 + r) * H_ + k0 + tx] = f2bf(tile[tx][r]);
    }
}

__global__ void cvt_bf16(const float* __restrict__ x, unsigned short* __restrict__ xb) {
    size_t i = ((size_t)blockIdx.x * 256 + threadIdx.x) * 4;
    fvec4 v = *(const fvec4*)&x[i];
    u16x4 o;
    o[0] = f2bf(v[0]); o[1] = f2bf(v[1]); o[2] = f2bf(v[2]); o[3] = f2bf(v[3]);
    *(u16x4*)&xb[i] = o;
}

// ---------------- big GEMM (layer-0 input gates), blocked Gi output ------------
// Gi u16 index = ((blk*256 + t)*4 + g)*1024 + b*16 + cl   (blk=(col&511)>>4, cl=col&15)
__global__ __launch_bounds__(256) void gemm_bt(
    const unsigned short* __restrict__ A, const unsigned short* __restrict__ Bt,
    const float* __restrict__ bias1, const float* __restrict__ bias2,
    unsigned short* __restrict__ C) {
    const int tid = threadIdx.x;
    const int wave = tid >> 6, lane = tid & 63;
    const int quad = lane >> 4, l15 = lane & 15;
    const int row0 = blockIdx.x * 64 + wave * 16;
    const int col0 = blockIdx.y * 64;
    f32x4 acc[4] = {};
    const unsigned short* ap = A + (size_t)(row0 + l15) * H_ + (quad << 3);
    const unsigned short* bp = Bt + (size_t)(col0 + l15) * H_ + (quad << 3);
#pragma unroll
    for (int kk = 0; kk < H_; kk += 32) {
        short8 a = *(const short8*)(ap + kk);
#pragma unroll
        for (int c4 = 0; c4 < 4; ++c4) {
            short8 b = *(const short8*)(bp + (size_t)(c4 << 4) * H_ + kk);
            acc[c4] = __builtin_amdgcn_mfma_f32_16x16x32_bf16(a, b, acc[c4], 0, 0, 0);
        }
    }
#pragma unroll
    for (int c4 = 0; c4 < 4; ++c4) {
        int col = col0 + (c4 << 4) + l15;
        float bs = bias1[col] + bias2[col];
        int g = col >> 9;
        int blk = (col & 511) >> 4;
#pragma unroll
        for (int r = 0; r < 4; ++r) {
            int row = row0 + (quad << 2) + r;
            int t = row & 255, b = row >> 8;
            C[((size_t)blk << 20) + ((size_t)t << 12) + (g << 10) + (b << 4) + l15] =
                f2bf(acc[c4][r] + bs);
        }
    }
}

// ---------------- combined persistent 2-layer recurrent kernel ----------------
// 32 WGs x 256 thr; WG slot s owns gate-cols [s*16,s*16+16) of BOTH layers.
// Round r (0..T): L0 computes h0(r) (if r<T), L1 computes h1(r-1) (if r>0).
// Both parts consume the SAME h0(r-1) tile -> one read serves two GEMM uses.
// Weights: Wh1 in VGPRs; Wh0 + Wi1 in LDS (128KB, fragment-linear).
// ONE publish (h0+h1 stores -> drain -> lane0 flag store) and ONE 32-flag
// cohort poll per round. Histories are write-once; plain b128 payload loads.
__global__ __launch_bounds__(256, 1) void lstm_fused(
    const unsigned short* __restrict__ Gi,   // blocked layer-0 gates (incl. biases)
    const unsigned short* __restrict__ Wt,   // 4 slabs: Wi0^T, Wi1^T, Wh0^T, Wh1^T
    unsigned* __restrict__ h0h,              // [T+1][32][64][8] u32 h0 history
    unsigned* __restrict__ h1h,              // [T+1][32][64][8] u32 h1 history
    const float* __restrict__ bi, const float* __restrict__ bh,
    float* __restrict__ out,                 // [B][T][512] f32 (layer-1 output)
    float* __restrict__ hT, float* __restrict__ cT,   // [L][B][512]
    unsigned* __restrict__ flags) {          // [slot*4+wave]*FPAD
    __shared__ unsigned short w_lds[2][64 * 512];   // 128KB: slab0=Wh0, slab1=Wi1
    const size_t NK = (size_t)NG * H_;
    const int tid = threadIdx.x;
    const int wave = tid >> 6, lane = tid & 63;
    const int quad = lane >> 4, l15 = lane & 15;
    const int m0 = wave << 4;
    const int slot = (int)blockIdx.x;
    const int j0 = slot << 4;
    const size_t hoff = ((size_t)(quad >> 1) << 9) + ((size_t)(m0 + l15) << 3) + ((quad & 1) << 2);
    const int wbase = (quad << 8) + (l15 << 4);

    // ---- Wh1 slab -> VGPRs ----
    const unsigned short* Wh1t = Wt + 3 * NK;
    short8 bw[64];
#pragma unroll
    for (int kb = 0; kb < 16; ++kb)
#pragma unroll
        for (int g = 0; g < 4; ++g)
            bw[kb * 4 + g] =
                *(const short8*)&Wh1t[(size_t)((g << 9) + j0 + l15) * H_ + (kb << 5) + (quad << 3)];
#pragma unroll
    for (int i = 0; i < 64; ++i) asm volatile("" : "+v"(bw[i]));

    // ---- Wh0 -> LDS slab0, Wi1 -> LDS slab1 (byte = kb*4096+g*1024+quad*256+l15*16) ----
    {
        const unsigned short* srcs[2] = {Wt + 2 * NK, Wt + 1 * NK};
#pragma unroll
        for (int i2 = 0; i2 < 32; ++i2) {
            int c = i2 * 256 + tid;            // 8192 x 16B chunks
            int sl = c >> 12, cc_ = c & 4095;
            int l = cc_ & 15, q = (cc_ >> 4) & 3, g = (cc_ >> 6) & 3, kb = cc_ >> 8;
            short8 v = *(const short8*)&srcs[sl][(size_t)((g << 9) + j0 + l) * H_ +
                                                 (kb << 5) + (q << 3)];
            *(short8*)((char*)&w_lds[sl][0] + ((size_t)cc_ << 4)) = v;
        }
    }

    // ---- zero slab 0 of both histories (each WG zeroes its slot block) ----
    store_coh(&h0h[(size_t)slot * 512 + tid], 0u);
    store_coh(&h0h[(size_t)slot * 512 + 256 + tid], 0u);
    store_coh(&h1h[(size_t)slot * 512 + tid], 0u);
    store_coh(&h1h[(size_t)slot * 512 + 256 + tid], 0u);
    __syncthreads();   // LDS staged + all waves' zero stores drained
    if (lane == 0) store_coh(&flags[(size_t)((slot << 2) + wave) * FPAD], 1u);

    // ---- biases (L1; L0's are baked into Gi) ----
    float gb0 = bi[NG + j0 + l15]        + bh[NG + j0 + l15];
    float gb1 = bi[NG + 512 + j0 + l15]  + bh[NG + 512 + j0 + l15];
    float gb2 = bi[NG + 1024 + j0 + l15] + bh[NG + 1024 + j0 + l15];
    float gb3 = bi[NG + 1536 + j0 + l15] + bh[NG + 1536 + j0 + l15];

    // ---- preload Gi[0] ----
    float gv[4][4];
#pragma unroll
    for (int r = 0; r < 4; ++r) {
        int b = m0 + (quad << 2) + r;
#pragma unroll
        for (int g = 0; g < 4; ++g)
            gv[g][r] = bf2f(Gi[((size_t)slot << 20) + (g << 10) + (b << 4) + l15]);
    }

    float cc0[4] = {0.f, 0.f, 0.f, 0.f};   // layer-0 cell state
    float cc1[4] = {0.f, 0.f, 0.f, 0.f};   // layer-1 cell state

    for (int rnd = 0; rnd <= T_; ++rnd) {
        wv_wait(flags, wave, (unsigned)(rnd + 1));

        // h0(rnd-1) from slab rnd — serves BOTH L0's Wh-part and L1's Wi-part
        const unsigned* ap0 = h0h + ((size_t)rnd << 14) + hoff;
        short8 ha0[16];
#pragma unroll
        for (int kb = 0; kb < 16; ++kb) ha0[kb] = *(const short8*)(ap0 + (kb << 10));
        short8 ha1[16];
        if (rnd > 0) {
            const unsigned* ap1 = h1h + ((size_t)(rnd - 1) << 14) + hoff;
#pragma unroll
            for (int kb = 0; kb < 16; ++kb) ha1[kb] = *(const short8*)(ap1 + (kb << 10));
        }

        // ---------- layer 0: h0(rnd) ----------
        if (rnd < T_) {
            f32x4 a0 = {}, a1 = {}, a2 = {}, a3 = {};
#pragma unroll
            for (int kb = 0; kb < 16; ++kb) {
                const char* base = (const char*)&w_lds[0][0] + (kb << 12) + wbase;
                short8 w0 = *(const short8*)(base);
                short8 w1 = *(const short8*)(base + (1 << 10));
                short8 w2 = *(const short8*)(base + (2 << 10));
                short8 w3 = *(const short8*)(base + (3 << 10));
                a0 = __builtin_amdgcn_mfma_f32_16x16x32_bf16(ha0[kb], w0, a0, 0, 0, 0);
                a1 = __builtin_amdgcn_mfma_f32_16x16x32_bf16(ha0[kb], w1, a1, 0, 0, 0);
                a2 = __builtin_amdgcn_mfma_f32_16x16x32_bf16(ha0[kb], w2, a2, 0, 0, 0);
                a3 = __builtin_amdgcn_mfma_f32_16x16x32_bf16(ha0[kb], w3, a3, 0, 0, 0);
            }
            unsigned* hw0 = h0h + ((size_t)(rnd + 1) << 14) + ((size_t)(slot * 64) << 3) + (l15 >> 1);
            float hvv[4];
#pragma unroll
            for (int r = 0; r < 4; ++r) {
                float iv = sigm(a0[r] + gv[0][r]);
                float fv = sigm(a1[r] + gv[1][r]);
                float gg = tanh_f(a2[r] + gv[2][r]);
                float ov = sigm(a3[r] + gv[3][r]);
                float cn = fv * cc0[r] + iv * gg;
                cc0[r] = cn;
                float hv = ov * tanh_f(cn);
                hvv[r] = hv;
                unsigned short hb16 = f2bf(hv);
                unsigned packed = (unsigned)hb16 |
                                  (((unsigned)(unsigned short)__shfl_xor((int)hb16, 1)) << 16);
                if (!(l15 & 1))
                    store_coh(&hw0[(size_t)(m0 + (quad << 2) + r) << 3], packed);
            }
            if (rnd == T_ - 1) {
#pragma unroll
                for (int r = 0; r < 4; ++r) {
                    int b = m0 + (quad << 2) + r;
                    int jj = j0 + l15;
                    hT[((size_t)b << 9) + jj] = hvv[r];
                    cT[((size_t)b << 9) + jj] = cc0[r];
                }
            }
        }

        // ---------- layer 1: h1(rnd-1) ----------
        float hv1[4];
        if (rnd > 0) {
            f32x4 a0 = {}, a1 = {}, a2 = {}, a3 = {};
#pragma unroll
            for (int kb = 0; kb < 16; ++kb) {
                a0 = __builtin_amdgcn_mfma_f32_16x16x32_bf16(ha1[kb], bw[kb * 4 + 0], a0, 0, 0, 0);
                a1 = __builtin_amdgcn_mfma_f32_16x16x32_bf16(ha1[kb], bw[kb * 4 + 1], a1, 0, 0, 0);
                a2 = __builtin_amdgcn_mfma_f32_16x16x32_bf16(ha1[kb], bw[kb * 4 + 2], a2, 0, 0, 0);
                a3 = __builtin_amdgcn_mfma_f32_16x16x32_bf16(ha1[kb], bw[kb * 4 + 3], a3, 0, 0, 0);
            }
#pragma unroll
            for (int kb = 0; kb < 16; ++kb) {
                const char* base = (const char*)&w_lds[1][0] + (kb << 12) + wbase;
                short8 w0 = *(const short8*)(base);
                short8 w1 = *(const short8*)(base + (1 << 10));
                short8 w2 = *(const short8*)(base + (2 << 10));
                short8 w3 = *(const short8*)(base + (3 << 10));
                a0 = __builtin_amdgcn_mfma_f32_16x16x32_bf16(ha0[kb], w0, a0, 0, 0, 0);
                a1 = __builtin_amdgcn_mfma_f32_16x16x32_bf16(ha0[kb], w1, a1, 0, 0, 0);
                a2 = __builtin_amdgcn_mfma_f32_16x16x32_bf16(ha0[kb], w2, a2, 0, 0, 0);
                a3 = __builtin_amdgcn_mfma_f32_16x16x32_bf16(ha0[kb], w3, a3, 0, 0, 0);
            }
            unsigned* hw1 = h1h + ((size_t)rnd << 14) + ((size_t)(slot * 64) << 3) + (l15 >> 1);
#pragma unroll
            for (int r = 0; r < 4; ++r) {
                float iv = sigm(a0[r] + gb0);
                float fv = sigm(a1[r] + gb1);
                float gg = tanh_f(a2[r] + gb2);
                float ov = sigm(a3[r] + gb3);
                float cn = fv * cc1[r] + iv * gg;
                cc1[r] = cn;
                float hv = ov * tanh_f(cn);
                hv1[r] = hv;
                unsigned short hb16 = f2bf(hv);
                unsigned packed = (unsigned)hb16 |
                                  (((unsigned)(unsigned short)__shfl_xor((int)hb16, 1)) << 16);
                if (!(l15 & 1))
                    store_coh(&hw1[(size_t)(m0 + (quad << 2) + r) << 3], packed);
            }
        }

        // ---------- single publish for the round ----------
        if (rnd < T_) {
            drain_vm();   // h0(rnd) + h1(rnd-1) stores acked
            if (lane == 0) store_coh(&flags[(size_t)((slot << 2) + wave) * FPAD],
                                     (unsigned)(rnd + 2));
        }

        // ---------- post-publish (off the cohort-visible path) ----------
        if (rnd > 0) {
            int t1 = rnd - 1;
#pragma unroll
            for (int r = 0; r < 4; ++r) {
                int b = m0 + (quad << 2) + r;
                int jj = j0 + l15;
                out[((size_t)((b << 8) + t1)) * H_ + jj] = hv1[r];
            }
            if (rnd == T_) {
#pragma unroll
                for (int r = 0; r < 4; ++r) {
                    int b = m0 + (quad << 2) + r;
                    int jj = j0 + l15;
                    hT[BH + ((size_t)b << 9) + jj] = hv1[r];
                    cT[BH + ((size_t)b << 9) + jj] = cc1[r];
                }
            }
        }
        if (rnd + 1 < T_) {
            // prefetch Gi[rnd+1] (in flight during next poll)
#pragma unroll
            for (int r = 0; r < 4; ++r) {
                int b = m0 + (quad << 2) + r;
#pragma unroll
                for (int g = 0; g < 4; ++g)
                    gv[g][r] = bf2f(Gi[((size_t)slot << 20) + ((size_t)(rnd + 1) << 12) +
                                       (g << 10) + (b << 4) + l15]);
            }
        }
    }
}

extern "C" void kernel_launch(void* const* d_in, const int* in_sizes, int n_in,
                              void* d_out, int out_size, void* d_ws, size_t ws_size,
                              hipStream_t stream) {
    const float* x  = (const float*)d_in[0];
    const float* Wi = (const float*)d_in[1];
    const float* Wh = (const float*)d_in[2];
    const float* bi = (const float*)d_in[3];
    const float* bh = (const float*)d_in[4];
    float* out = (float*)d_out;

    char* w = (char*)d_ws;
    const size_t NK = (size_t)NG * H_;
    unsigned short* Wt  = (unsigned short*)w;                  // 8 MB (4 slabs)
    unsigned short* xb  = Wt + 4 * NK;                         // 16 MB
    unsigned short* Gi  = xb + (size_t)16384 * H_;             // 64 MB (blocked layout)
    unsigned* h0h       = (unsigned*)(Gi + (size_t)16384 * NG);// (T+1)*16384 u32 = 16.85 MB
    unsigned* h1h       = h0h + (size_t)(T_ + 1) * 16384;      // 16.85 MB
    unsigned* flags     = h1h + (size_t)(T_ + 1) * 16384;      // 128 slots * 256B = 32 KB

    hipMemsetAsync(flags, 0, 128 * FPAD * sizeof(unsigned), stream);

    transpose_cvt<<<dim3(8, 32, 4), 256, 0, stream>>>(Wi, Wh, Wt);
    cvt_bf16<<<8192, 256, 0, stream>>>(x, xb);

    // layer-0 input gates (bulk GEMM, biases baked in, blocked output)
    gemm_bt<<<dim3(256, 32), 256, 0, stream>>>(xb, Wt + 0 * NK, bi, bh, Gi);

    // combined 2-layer recurrence: one cohort, one publish+poll per round
    lstm_fused<<<32, 256, 0, stream>>>(Gi, Wt, h0h, h1h, bi, bh,
                                       out, out + BTH, out + BTH + 2 * (size_t)BH, flags);
}

// Round 11
// 2154.244 us; speedup vs baseline: 4.4164x; 1.1446x over previous
//
#include <hip/hip_runtime.h>

typedef __attribute__((ext_vector_type(8))) short short8;
typedef __attribute__((ext_vector_type(4))) float f32x4;
typedef __attribute__((ext_vector_type(4))) float fvec4;
typedef __attribute__((ext_vector_type(4))) unsigned short u16x4;

#define B_ 64
#define T_ 256
#define H_ 512
#define NG 2048   // 4*H
#define BTH (64*256*512)
#define BH (64*512)
#define FPAD 64   // 256B per flag slot -> distinct L3 lines

__device__ __forceinline__ float bf2f(unsigned short u) {
    return __builtin_bit_cast(float, ((unsigned)u) << 16);
}
__device__ __forceinline__ unsigned short f2bf(float f) {
    unsigned u = __builtin_bit_cast(unsigned, f);
    u += 0x7fffu + ((u >> 16) & 1u);   // RNE
    return (unsigned short)(u >> 16);
}
__device__ __forceinline__ float sigm(float x) { return 1.f / (1.f + __expf(-x)); }
__device__ __forceinline__ float tanh_f(float x) {
    x = fminf(15.f, fmaxf(-15.f, x));
    float e = __expf(-2.f * x);
    return (1.f - e) / (1.f + e);
}

__device__ __forceinline__ void store_coh(unsigned* p, unsigned v) {
    __hip_atomic_store(p, v, __ATOMIC_RELAXED, __HIP_MEMORY_SCOPE_AGENT);
}
// drain this wave's outstanding vmem ops (stores acked at coherence point)
__device__ __forceinline__ void drain_vm() {
    asm volatile("s_waitcnt vmcnt(0)" ::: "memory");
}
// wave-cohort wait: poll the 32 flags of wave-index w across the 32 WG slots.
__device__ __forceinline__ void wv_wait(const unsigned* fl, int w, unsigned target) {
    const unsigned* p = fl + (size_t)(((threadIdx.x & 31) << 2) + w) * FPAD;
    int spins = 0;
    for (;;) {
        unsigned v = __hip_atomic_load(p, __ATOMIC_RELAXED, __HIP_MEMORY_SCOPE_AGENT);
        if (__all((int)(v >= target))) break;
        __builtin_amdgcn_s_sleep(1);
        if (++spins > 400000) break;   // failsafe: wrong answer, not hang
    }
    asm volatile("" ::: "memory");     // no hoisting of data loads above the poll
}

// ---------------- prep: weight transpose f32[K,N] -> bf16[N,K] ----------------
__global__ void transpose_cvt(const float* __restrict__ Wi, const float* __restrict__ Wh,
                              unsigned short* __restrict__ Wt) {
    __shared__ float tile[64][65];
    int z = blockIdx.z;
    const float* src = (z < 2 ? Wi : Wh) + (size_t)(z & 1) * H_ * NG;
    unsigned short* dst = Wt + (size_t)z * NG * H_;
    int k0 = blockIdx.x * 64, n0 = blockIdx.y * 64;
    int tx = threadIdx.x & 63, ty = threadIdx.x >> 6;
#pragma unroll
    for (int p = 0; p < 16; ++p) {
        int r = (p << 2) + ty;
        tile[r][tx] = src[(size_t)(k0 + r) * NG + n0 + tx];
    }
    __syncthreads();
#pragma unroll
    for (int p = 0; p < 16; ++p) {
        int r = (p << 2) + ty;
        dst[(size_t)(n0 + r) * H_ + k0 + tx] = f2bf(tile[tx][r]);
    }
}

__global__ void cvt_bf16(const float* __restrict__ x, unsigned short* __restrict__ xb) {
    size_t i = ((size_t)blockIdx.x * 256 + threadIdx.x) * 4;
    fvec4 v = *(const fvec4*)&x[i];
    u16x4 o;
    o[0] = f2bf(v[0]); o[1] = f2bf(v[1]); o[2] = f2bf(v[2]); o[3] = f2bf(v[3]);
    *(u16x4*)&xb[i] = o;
}

// ---------------- big GEMM (layer-0 input gates), blocked Gi output ------------
// Gi u16 index = ((blk*256 + t)*4 + g)*1024 + b*16 + cl   (blk=(col&511)>>4, cl=col&15)
__global__ __launch_bounds__(256) void gemm_bt(
    const unsigned short* __restrict__ A, const unsigned short* __restrict__ Bt,
    const float* __restrict__ bias1, const float* __restrict__ bias2,
    unsigned short* __restrict__ C) {
    const int tid = threadIdx.x;
    const int wave = tid >> 6, lane = tid & 63;
    const int quad = lane >> 4, l15 = lane & 15;
    const int row0 = blockIdx.x * 64 + wave * 16;
    const int col0 = blockIdx.y * 64;
    f32x4 acc[4] = {};
    const unsigned short* ap = A + (size_t)(row0 + l15) * H_ + (quad << 3);
    const unsigned short* bp = Bt + (size_t)(col0 + l15) * H_ + (quad << 3);
#pragma unroll
    for (int kk = 0; kk < H_; kk += 32) {
        short8 a = *(const short8*)(ap + kk);
#pragma unroll
        for (int c4 = 0; c4 < 4; ++c4) {
            short8 b = *(const short8*)(bp + (size_t)(c4 << 4) * H_ + kk);
            acc[c4] = __builtin_amdgcn_mfma_f32_16x16x32_bf16(a, b, acc[c4], 0, 0, 0);
        }
    }
#pragma unroll
    for (int c4 = 0; c4 < 4; ++c4) {
        int col = col0 + (c4 << 4) + l15;
        float bs = bias1[col] + bias2[col];
        int g = col >> 9;
        int blk = (col & 511) >> 4;
#pragma unroll
        for (int r = 0; r < 4; ++r) {
            int row = row0 + (quad << 2) + r;
            int t = row & 255, b = row >> 8;
            C[((size_t)blk << 20) + ((size_t)t << 12) + (g << 10) + (b << 4) + l15] =
                f2bf(acc[c4][r] + bs);
        }
    }
}

// ---------------- fused persistent 2-layer recurrent kernel ----------------
// 64 WGs x 256 thr. WGs 0..31: layer 0; WGs 32..63: layer 1 (lags >=1 step; h0
// full history means layer 0 NEVER waits on layer 1).
// h layout (slot-major, u32-packed bf16): h[t][slot 0..31][b 0..63][8 u32].
// Sync: PER-WAVE flags. Producer: sc1 data stores -> s_waitcnt vmcnt(0) ->
// LANE-0 flag store (single store: no same-address serialization). All other
// global stores (out, hT, cT, Gi prefetch) are issued AFTER the flag publish
// so the drain covers ONLY the 4 h stores. No __syncthreads in steady loop.
__global__ __launch_bounds__(256, 1) void lstm_fused(
    const unsigned short* __restrict__ Gi,   // blocked layer-0 gates (incl. biases)
    const unsigned short* __restrict__ Wt,   // 4 slabs: Wi0^T, Wi1^T, Wh0^T, Wh1^T
    unsigned* __restrict__ h0h,              // [T+1][32][64][8] u32 h0 history
    unsigned* __restrict__ h1h,              // [T+1][32][64][8] u32 h1 history
    const float* __restrict__ bi, const float* __restrict__ bh,
    float* __restrict__ out,                 // [B][T][512] f32 (layer-1 output)
    float* __restrict__ hT, float* __restrict__ cT,   // [L][B][512]
    unsigned* __restrict__ flags) {          // [layer][slot*4+wave]*FPAD
    __shared__ unsigned short wi_lds[64 * 512];   // 64KB, fragment-linear layout
    const size_t NK = (size_t)NG * H_;
    const int tid = threadIdx.x;
    const int wave = tid >> 6, lane = tid & 63;
    const int quad = lane >> 4, l15 = lane & 15;
    const int m0 = wave << 4;
    unsigned* flag0 = flags;
    unsigned* flag1 = flags + 128 * FPAD;
    // per-lane offset into a t-slab of the h history (reader side)
    const size_t hoff = ((size_t)(quad >> 1) << 9) + ((size_t)(m0 + l15) << 3) + ((quad & 1) << 2);

    if (blockIdx.x < 32) {
        // ================= layer 0 =================
        const int slot = (int)blockIdx.x;
        const int j0 = slot << 4;
        const unsigned short* Wht = Wt + 2 * NK;
        short8 bw[64];
#pragma unroll
        for (int kb = 0; kb < 16; ++kb)
#pragma unroll
            for (int g = 0; g < 4; ++g)
                bw[kb * 4 + g] =
                    *(const short8*)&Wht[(size_t)((g << 9) + j0 + l15) * H_ + (kb << 5) + (quad << 3)];
#pragma unroll
        for (int i = 0; i < 64; ++i) asm volatile("" : "+v"(bw[i]));

        // zero own rows of h0 slot 0 (contiguous slot-major layout)
        if (!(l15 & 1)) {
            unsigned* hz = h0h + ((size_t)(slot * 64) << 3) + (l15 >> 1);
#pragma unroll
            for (int r = 0; r < 4; ++r)
                store_coh(&hz[(size_t)(m0 + (quad << 2) + r) << 3], 0u);
        }
        float cc[4] = {0.f, 0.f, 0.f, 0.f};
        drain_vm();
        if (lane == 0) store_coh(&flag0[(size_t)((slot << 2) + wave) * FPAD], 1u);

        // preload Gi[0] (blocked layout; consumed at elementwise of t=0)
        float gv[4][4];
#pragma unroll
        for (int r = 0; r < 4; ++r) {
            int b = m0 + (quad << 2) + r;
#pragma unroll
            for (int g = 0; g < 4; ++g)
                gv[g][r] = bf2f(Gi[((size_t)slot << 20) + (g << 10) + (b << 4) + l15]);
        }

        for (int t = 0; t < T_; ++t) {
            wv_wait(flag0, wave, (unsigned)(t + 1));
            const unsigned* ap = h0h + ((size_t)t << 14) + hoff;
            short8 ha[16];
#pragma unroll
            for (int kb = 0; kb < 16; ++kb) ha[kb] = *(const short8*)(ap + (kb << 10));

            f32x4 acc0 = {}, acc1 = {}, acc2 = {}, acc3 = {};
#pragma unroll
            for (int kb = 0; kb < 16; ++kb) {
                acc0 = __builtin_amdgcn_mfma_f32_16x16x32_bf16(ha[kb], bw[kb * 4 + 0], acc0, 0, 0, 0);
                acc1 = __builtin_amdgcn_mfma_f32_16x16x32_bf16(ha[kb], bw[kb * 4 + 1], acc1, 0, 0, 0);
                acc2 = __builtin_amdgcn_mfma_f32_16x16x32_bf16(ha[kb], bw[kb * 4 + 2], acc2, 0, 0, 0);
                acc3 = __builtin_amdgcn_mfma_f32_16x16x32_bf16(ha[kb], bw[kb * 4 + 3], acc3, 0, 0, 0);
            }

            unsigned* hw = h0h + ((size_t)(t + 1) << 14) + ((size_t)(slot * 64) << 3) + (l15 >> 1);
            float hvv[4];
#pragma unroll
            for (int r = 0; r < 4; ++r) {
                float iv = sigm(acc0[r] + gv[0][r]);
                float fv = sigm(acc1[r] + gv[1][r]);
                float gg = tanh_f(acc2[r] + gv[2][r]);
                float ov = sigm(acc3[r] + gv[3][r]);
                float cn = fv * cc[r] + iv * gg;
                cc[r] = cn;
                float hv = ov * tanh_f(cn);
                hvv[r] = hv;
                unsigned short hb16 = f2bf(hv);
                unsigned packed = (unsigned)hb16 |
                                  (((unsigned)(unsigned short)__shfl_xor((int)hb16, 1)) << 16);
                if (!(l15 & 1))
                    store_coh(&hw[(size_t)(m0 + (quad << 2) + r) << 3], packed);
            }
            drain_vm();   // ONLY the 4 h stores outstanding here
            if (lane == 0)
                store_coh(&flag0[(size_t)((slot << 2) + wave) * FPAD], (unsigned)(t + 2));

            // post-publish: prefetch / tail stores (off the cohort-visible path)
            if (t < T_ - 1) {
#pragma unroll
                for (int r = 0; r < 4; ++r) {
                    int b = m0 + (quad << 2) + r;
#pragma unroll
                    for (int g = 0; g < 4; ++g)
                        gv[g][r] = bf2f(Gi[((size_t)slot << 20) + ((size_t)(t + 1) << 12) +
                                           (g << 10) + (b << 4) + l15]);
                }
            } else {
#pragma unroll
                for (int r = 0; r < 4; ++r) {
                    int b = m0 + (quad << 2) + r;
                    int jj = j0 + l15;
                    hT[((size_t)b << 9) + jj] = hvv[r];
                    cT[((size_t)b << 9) + jj] = cc[r];
                }
            }
        }
    } else {
        // ================= layer 1 =================
        const int slot = (int)blockIdx.x - 32;
        const int j0 = slot << 4;
        const unsigned short* Wht = Wt + 3 * NK;
        short8 bw[64];
#pragma unroll
        for (int kb = 0; kb < 16; ++kb)
#pragma unroll
            for (int g = 0; g < 4; ++g)
                bw[kb * 4 + g] =
                    *(const short8*)&Wht[(size_t)((g << 9) + j0 + l15) * H_ + (kb << 5) + (quad << 3)];
#pragma unroll
        for (int i = 0; i < 64; ++i) asm volatile("" : "+v"(bw[i]));

        // stage Wi1 slab into LDS (byte = kb*4096 + g*1024 + quad*256 + l15*16)
        const unsigned short* Wit = Wt + 1 * NK;
#pragma unroll
        for (int i2 = 0; i2 < 16; ++i2) {
            int c = i2 * 256 + tid;            // 4096 x 16B chunks
            int l = c & 15, q = (c >> 4) & 3, g = (c >> 6) & 3, kb = c >> 8;
            short8 v = *(const short8*)&Wit[(size_t)((g << 9) + j0 + l) * H_ + (kb << 5) + (q << 3)];
            *(short8*)((char*)wi_lds + ((size_t)c << 4)) = v;
        }
        __syncthreads();   // one-time: LDS staging visible to all waves
        const int wbase = (quad << 8) + (l15 << 4);

        float gb0 = bi[NG + j0 + l15]        + bh[NG + j0 + l15];
        float gb1 = bi[NG + 512 + j0 + l15]  + bh[NG + 512 + j0 + l15];
        float gb2 = bi[NG + 1024 + j0 + l15] + bh[NG + 1024 + j0 + l15];
        float gb3 = bi[NG + 1536 + j0 + l15] + bh[NG + 1536 + j0 + l15];

        // zero own rows of h1 slot 0
        if (!(l15 & 1)) {
            unsigned* hz = h1h + ((size_t)(slot * 64) << 3) + (l15 >> 1);
#pragma unroll
            for (int r = 0; r < 4; ++r)
                store_coh(&hz[(size_t)(m0 + (quad << 2) + r) << 3], 0u);
        }
        float cc[4] = {0.f, 0.f, 0.f, 0.f};
        drain_vm();
        if (lane == 0) store_coh(&flag1[(size_t)((slot << 2) + wave) * FPAD], 1u);

        // prologue: h1(-1) from slot 0, h0(0) from slot 1
        short8 ha1[16], ha0[16];
        wv_wait(flag1, wave, 1u);
        {
            const unsigned* ap1 = h1h + hoff;
#pragma unroll
            for (int kb = 0; kb < 16; ++kb) ha1[kb] = *(const short8*)(ap1 + (kb << 10));
        }
        wv_wait(flag0, wave, 2u);
        {
            const unsigned* ap0 = h0h + ((size_t)1 << 14) + hoff;
#pragma unroll
            for (int kb = 0; kb < 16; ++kb) ha0[kb] = *(const short8*)(ap0 + (kb << 10));
        }

        for (int t = 0; t < T_; ++t) {
            f32x4 acc0 = {}, acc1 = {}, acc2 = {}, acc3 = {};
            // Wh1 x h1(t-1) (register B-frags)
#pragma unroll
            for (int kb = 0; kb < 16; ++kb) {
                acc0 = __builtin_amdgcn_mfma_f32_16x16x32_bf16(ha1[kb], bw[kb * 4 + 0], acc0, 0, 0, 0);
                acc1 = __builtin_amdgcn_mfma_f32_16x16x32_bf16(ha1[kb], bw[kb * 4 + 1], acc1, 0, 0, 0);
                acc2 = __builtin_amdgcn_mfma_f32_16x16x32_bf16(ha1[kb], bw[kb * 4 + 2], acc2, 0, 0, 0);
                acc3 = __builtin_amdgcn_mfma_f32_16x16x32_bf16(ha1[kb], bw[kb * 4 + 3], acc3, 0, 0, 0);
            }
            // Wi1 x h0(t) (B-frags from LDS)
#pragma unroll
            for (int kb = 0; kb < 16; ++kb) {
                const char* base = (const char*)wi_lds + (kb << 12) + wbase;
                short8 w0 = *(const short8*)(base);
                short8 w1 = *(const short8*)(base + (1 << 10));
                short8 w2 = *(const short8*)(base + (2 << 10));
                short8 w3 = *(const short8*)(base + (3 << 10));
                acc0 = __builtin_amdgcn_mfma_f32_16x16x32_bf16(ha0[kb], w0, acc0, 0, 0, 0);
                acc1 = __builtin_amdgcn_mfma_f32_16x16x32_bf16(ha0[kb], w1, acc1, 0, 0, 0);
                acc2 = __builtin_amdgcn_mfma_f32_16x16x32_bf16(ha0[kb], w2, acc2, 0, 0, 0);
                acc3 = __builtin_amdgcn_mfma_f32_16x16x32_bf16(ha0[kb], w3, acc3, 0, 0, 0);
            }

            unsigned* hw = h1h + ((size_t)(t + 1) << 14) + ((size_t)(slot * 64) << 3) + (l15 >> 1);
            float hvv[4];
#pragma unroll
            for (int r = 0; r < 4; ++r) {
                float iv = sigm(acc0[r] + gb0);
                float fv = sigm(acc1[r] + gb1);
                float gg = tanh_f(acc2[r] + gb2);
                float ov = sigm(acc3[r] + gb3);
                float cn = fv * cc[r] + iv * gg;
                cc[r] = cn;
                float hv = ov * tanh_f(cn);
                hvv[r] = hv;
                unsigned short hb16 = f2bf(hv);
                unsigned packed = (unsigned)hb16 |
                                  (((unsigned)(unsigned short)__shfl_xor((int)hb16, 1)) << 16);
                if (!(l15 & 1))
                    store_coh(&hw[(size_t)(m0 + (quad << 2) + r) << 3], packed);
            }

            if (t < T_ - 1) {
                drain_vm();   // ONLY the 4 h stores outstanding
                if (lane == 0)
                    store_coh(&flag1[(size_t)((slot << 2) + wave) * FPAD], (unsigned)(t + 2));
            }

            // post-publish: out stores overlap peers' polls / our own waits
#pragma unroll
            for (int r = 0; r < 4; ++r) {
                int b = m0 + (quad << 2) + r;
                int jj = j0 + l15;
                out[((size_t)((b << 8) + t)) * H_ + jj] = hvv[r];
            }
            if (t == T_ - 1) {
#pragma unroll
                for (int r = 0; r < 4; ++r) {
                    int b = m0 + (quad << 2) + r;
                    int jj = j0 + l15;
                    hT[BH + ((size_t)b << 9) + jj] = hvv[r];
                    cT[BH + ((size_t)b << 9) + jj] = cc[r];
                }
                break;   // nobody consumes h1(T) / flag1(T+1)
            }

            // h0(t+1): layer 0 runs ahead -> wait ~instant, loads fly during flag1 poll
            wv_wait(flag0, wave, (unsigned)(t + 3));
            const unsigned* ap0 = h0h + ((size_t)(t + 2) << 14) + hoff;
#pragma unroll
            for (int kb = 0; kb < 16; ++kb) ha0[kb] = *(const short8*)(ap0 + (kb << 10));
            // h1(t): own wave-cohort
            wv_wait(flag1, wave, (unsigned)(t + 2));
            const unsigned* ap1 = h1h + ((size_t)(t + 1) << 14) + hoff;
#pragma unroll
            for (int kb = 0; kb < 16; ++kb) ha1[kb] = *(const short8*)(ap1 + (kb << 10));
        }
    }
}

extern "C" void kernel_launch(void* const* d_in, const int* in_sizes, int n_in,
                              void* d_out, int out_size, void* d_ws, size_t ws_size,
                              hipStream_t stream) {
    const float* x  = (const float*)d_in[0];
    const float* Wi = (const float*)d_in[1];
    const float* Wh = (const float*)d_in[2];
    const float* bi = (const float*)d_in[3];
    const float* bh = (const float*)d_in[4];
    float* out = (float*)d_out;

    char* w = (char*)d_ws;
    const size_t NK = (size_t)NG * H_;
    unsigned short* Wt  = (unsigned short*)w;                  // 8 MB (4 slabs)
    unsigned short* xb  = Wt + 4 * NK;                         // 16 MB
    unsigned short* Gi  = xb + (size_t)16384 * H_;             // 64 MB (blocked layout)
    unsigned* h0h       = (unsigned*)(Gi + (size_t)16384 * NG);// (T+1)*16384 u32 = 16.85 MB
    unsigned* h1h       = h0h + (size_t)(T_ + 1) * 16384;      // 16.85 MB
    unsigned* flags     = h1h + (size_t)(T_ + 1) * 16384;      // 2*128*256B = 128 KB

    hipMemsetAsync(flags, 0, 2 * 128 * FPAD * sizeof(unsigned), stream);

    transpose_cvt<<<dim3(8, 32, 4), 256, 0, stream>>>(Wi, Wh, Wt);
    cvt_bf16<<<8192, 256, 0, stream>>>(x, xb);

    // layer-0 input gates (bulk GEMM, biases baked in, blocked output)
    gemm_bt<<<dim3(256, 32), 256, 0, stream>>>(xb, Wt + 0 * NK, bi, bh, Gi);

    // fused pipelined 2-layer recurrence (wave-autonomous sync, lane-0 publish)
    lstm_fused<<<64, 256, 0, stream>>>(Gi, Wt, h0h, h1h, bi, bh,
                                       out, out + BTH, out + BTH + 2 * (size_t)BH, flags);
}